// Round 6
// baseline (25.398 us; speedup 1.0000x reference)
//
#include <hip/hip_runtime.h>

#define HH 512
#define WW 512
#define HWPIX (HH * WW)
#define BPB 32            // blocks per batch  (was 64 — amortize epilogue)
#define NB  32            // batches
#define NT  256
#define ITERS 8           // float4-groups per thread (was 4)

struct Partial {
    int   pa, va;          // plaque / vessel counts
    float pc, vc;          // conf-weighted sums
    int   rmin, rmax, cmin, cmax;  // plaque bbox
};

__global__ __launch_bounds__(NT)
void mfe_reduce(const float* __restrict__ in, Partial* __restrict__ part) {
    const int b = blockIdx.y, k = blockIdx.x, tid = threadIdx.x;

    const float4* p0 = (const float4*)(in + (size_t)b * 3 * HWPIX);
    const float4* p1 = p0 + (HWPIX / 4);
    const float4* p2 = p0 + (HWPIX / 2);

    int   cnt = 0;                 // pa | va<<16 (max 32/thread, 8192/block)
    float pc = 0.f, vc = 0.f;
    int   rmin = HH, rmax = -1, cmin = WW, cmax = -1;

    // g: float4 index; consecutive lanes -> consecutive float4 (1KB/instr, coalesced)
    int g = k * NT + tid;
    float4 a = p0[g], b4 = p1[g], c4 = p2[g];

    #pragma unroll
    for (int i = 0; i < ITERS; ++i) {
        const int gn = g + BPB * NT;
        float4 a_n, b_n, c_n;
        if (i < ITERS - 1) { a_n = p0[gn]; b_n = p1[gn]; c_n = p2[gn]; }

        const int row     = g >> 7;          // 128 float4 per 512-px row
        const int colbase = (g & 127) << 2;
        unsigned msk = 0u;
        const float* A = (const float*)&a;
        const float* B = (const float*)&b4;
        const float* C = (const float*)&c4;
        #pragma unroll
        for (int j = 0; j < 4; ++j) {
            float l0 = A[j], l1 = B[j], l2 = C[j];
            float m01 = fmaxf(l0, l1);
            float m   = fmaxf(m01, l2);
            float t0 = l0 - m, t1 = l1 - m, t2 = l2 - m;   // t_max == 0
            float tmin = fminf(fminf(t0, t1), t2);          // v_min3
            float tmid = ((t0 + t1) + t2) - tmin;           // mid = sum - min (max=0)
            float s    = 1.0f + __expf(tmid) + __expf(tmin);
            float conf = __builtin_amdgcn_rcpf(s);          // softmax prob of argmax
            bool isV = l2 > m01;                            // pred==2, first-index rule
            bool isP = (l1 > l0) && !isV;                   // pred==1
            cnt += (int)isP | ((int)isV << 16);
            pc  += isP ? conf : 0.f;
            vc  += isV ? conf : 0.f;
            msk |= (unsigned)isP << j;
        }
        if (msk) {
            rmin = min(rmin, row);
            rmax = max(rmax, row);
            cmin = min(cmin, colbase + (__ffs(msk) - 1));
            cmax = max(cmax, colbase + (31 - __clz(msk)));
        }
        a = a_n; b4 = b_n; c4 = c_n; g = gn;
    }

    // wave (64-lane) shuffle reduce: 7 channels
    #pragma unroll
    for (int off = 32; off > 0; off >>= 1) {
        cnt += __shfl_down(cnt, off, 64);
        pc  += __shfl_down(pc, off, 64);
        vc  += __shfl_down(vc, off, 64);
        rmin = min(rmin, __shfl_down(rmin, off, 64));
        rmax = max(rmax, __shfl_down(rmax, off, 64));
        cmin = min(cmin, __shfl_down(cmin, off, 64));
        cmax = max(cmax, __shfl_down(cmax, off, 64));
    }

    struct SPart { int cnt; float pc, vc; int rmin, rmax, cmin, cmax; };
    __shared__ SPart sp[NT / 64];
    const int lane = tid & 63, wid = tid >> 6;
    if (lane == 0) sp[wid] = SPart{cnt, pc, vc, rmin, rmax, cmin, cmax};
    __syncthreads();
    if (tid == 0) {
        SPart r = sp[0];
        #pragma unroll
        for (int w = 1; w < NT / 64; ++w) {
            r.cnt += sp[w].cnt;
            r.pc  += sp[w].pc;   r.vc += sp[w].vc;
            r.rmin = min(r.rmin, sp[w].rmin);
            r.rmax = max(r.rmax, sp[w].rmax);
            r.cmin = min(r.cmin, sp[w].cmin);
            r.cmax = max(r.cmax, sp[w].cmax);
        }
        part[b * BPB + k] = Partial{r.cnt & 0xFFFF, r.cnt >> 16, r.pc, r.vc,
                                    r.rmin, r.rmax, r.cmin, r.cmax};
    }
}

__global__ __launch_bounds__(64)
void mfe_finalize(const Partial* __restrict__ part, float* __restrict__ out) {
    const int b    = blockIdx.x;
    const int lane = threadIdx.x;
    // Only BPB=32 partials per batch: lanes 32..63 load neutral elements.
    Partial r;
    if (lane < BPB) r = part[b * BPB + lane];
    else            r = Partial{0, 0, 0.f, 0.f, HH, -1, WW, -1};
    int pa = r.pa, va = r.va;
    float pc = r.pc, vc = r.vc;
    int rmin = r.rmin, rmax = r.rmax, cmin = r.cmin, cmax = r.cmax;

    #pragma unroll
    for (int off = 32; off > 0; off >>= 1) {
        pa += __shfl_down(pa, off, 64);
        va += __shfl_down(va, off, 64);
        pc += __shfl_down(pc, off, 64);
        vc += __shfl_down(vc, off, 64);
        rmin = min(rmin, __shfl_down(rmin, off, 64));
        rmax = max(rmax, __shfl_down(rmax, off, 64));
        cmin = min(cmin, __shfl_down(cmin, off, 64));
        cmax = max(cmax, __shfl_down(cmax, off, 64));
    }

    if (lane == 0) {
        const float paf = (float)pa;
        const float vaf = (float)va;
        const float fa  = paf + vaf;                  // fg = plaque + vessel
        const bool  ne  = (rmax >= 0);
        const float hr  = ne ? (float)(rmax - rmin) : 0.f;
        const float wr  = ne ? (float)(cmax - cmin) : 0.f;
        float* o = out + b * 10;
        o[0] = paf / (vaf + 1e-6f);
        o[1] = paf / (fa + 1e-6f);
        o[2] = pc;
        o[3] = hr / (float)HH;
        o[4] = wr / (float)WW;
        o[5] = 2.0f * (hr + wr) / (float)(HH + WW);
        o[6] = vc;
        o[7] = (pa > 0) ? (pc / (paf + 1e-6f)) : 0.f;
        o[8] = fa / (float)HWPIX;
        o[9] = paf / (float)HWPIX;
    }
}

extern "C" void kernel_launch(void* const* d_in, const int* in_sizes, int n_in,
                              void* d_out, int out_size, void* d_ws, size_t ws_size,
                              hipStream_t stream) {
    const float* in  = (const float*)d_in[0];
    float*       out = (float*)d_out;
    Partial*     part = (Partial*)d_ws;

    dim3 grid(BPB, NB);
    mfe_reduce<<<grid, NT, 0, stream>>>(in, part);
    mfe_finalize<<<NB, 64, 0, stream>>>(part, out);
}